// Round 8
// baseline (84.673 us; speedup 1.0000x reference)
//
#include <hip/hip_runtime.h>
#include <hip/hip_bf16.h>

#define B_ 8
#define N_ 2048
#define D_ 512
#define DK_ 64

typedef float f32x4 __attribute__((ext_vector_type(4)));
typedef short bf16x8 __attribute__((ext_vector_type(8)));
typedef unsigned short u16;

__device__ __forceinline__ u16 f2bf(float f) {
  union { float f; unsigned u; } v; v.f = f;
  unsigned r = v.u + 0x7FFFu + ((v.u >> 16) & 1u);  // RNE, inputs finite
  return (u16)(r >> 16);
}

#define MFMA16(a, b, cacc) __builtin_amdgcn_mfma_f32_16x16x32_bf16((a), (b), (cacc), 0, 0, 0)

// ===========================================================================
// Fragment layouts (every attn global load = 64 lanes x 16B contiguous 1KB):
//  Qf/Kf: elem((b*128 + slab)*2 + ks)*512 + lane*8 + i
//         holds  M[slab*16 + (lane&15)][ks*32 + (lane>>4)*8 + i]
//  Vf:    elem(((b*32 + dt)*32 + kvt)*2 + ks)*512 + lane*8 + i
//         holds  X[kvt*64 + ks*32 + (lane>>4)*8 + i][dt*16 + (lane&15)]
// ===========================================================================

// ---------------------------------------------------------------------------
// Kernel 1 (validated): X f32 -> Vf bf16 frag layout.
// ---------------------------------------------------------------------------
__global__ __launch_bounds__(256) void vt_kernel(const float* __restrict__ X,
                                                 u16* __restrict__ Vf) {
  int bid = blockIdx.x;
  int dt = bid & 7, nt = (bid >> 3) & 31, b = bid >> 8;
  int n0 = nt * 64, d0 = dt * 64;
  __shared__ u16 T[64 * 72];  // T[d_local][n_local]
  int t = threadIdx.x;
  const float* Xb = X + ((size_t)b * N_ + n0) * D_ + d0;
#pragma unroll
  for (int p = 0; p < 4; ++p) {
    int r = p * 16 + (t >> 4);      // n_local
    int c4 = (t & 15) * 4;          // d_local base
    f32x4 v = *reinterpret_cast<const f32x4*>(Xb + (size_t)r * D_ + c4);
#pragma unroll
    for (int j = 0; j < 4; ++j) T[(c4 + j) * 72 + r] = f2bf(v[j]);
  }
  __syncthreads();
  int w = t >> 6, l = t & 63, g = l >> 4, c = l & 15;
#pragma unroll
  for (int ks = 0; ks < 2; ++ks) {
    bf16x8 v = *reinterpret_cast<const bf16x8*>(&T[(w * 16 + c) * 72 + ks * 32 + 8 * g]);
    *reinterpret_cast<bf16x8*>(
        Vf + (((size_t)(b * 32 + dt * 4 + w) * 32 + nt) * 2 + ks) * 512 + l * 8) = v;
  }
}

// ---------------------------------------------------------------------------
// Kernel 2 (validated): Qf = (h@WQ + bQ)/8, Kf = X@WK + bK, frag layout.
// ---------------------------------------------------------------------------
__global__ __launch_bounds__(256) void proj_kernel(
    const float* __restrict__ h, const float* __restrict__ X,
    const float* __restrict__ WQ, const float* __restrict__ bQ,
    const float* __restrict__ WK, const float* __restrict__ bK,
    u16* __restrict__ Qf, u16* __restrict__ Kf) {
  int bid = blockIdx.x;
  int b = bid & 7, nt = bid >> 3;
  int n0 = nt * 64;
  int t = threadIdx.x, w = t >> 6, l = t & 63, g = l >> 4, c = l & 15;
  int arow = n0 + w * 16 + c;
  const float* hrow = h + ((size_t)b * N_ + arow) * D_;
  const float* Xrow = X + ((size_t)b * N_ + arow) * D_;
  f32x4 accq[4], acck[4];
#pragma unroll
  for (int cf = 0; cf < 4; ++cf) {
    accq[cf] = (f32x4){0.f, 0.f, 0.f, 0.f};
    acck[cf] = (f32x4){0.f, 0.f, 0.f, 0.f};
  }
  for (int k0 = 0; k0 < D_; k0 += 32) {
    bf16x8 ah, ax;
    {
      f32x4 h0 = *reinterpret_cast<const f32x4*>(hrow + k0 + 8 * g);
      f32x4 h1 = *reinterpret_cast<const f32x4*>(hrow + k0 + 8 * g + 4);
      f32x4 x0 = *reinterpret_cast<const f32x4*>(Xrow + k0 + 8 * g);
      f32x4 x1 = *reinterpret_cast<const f32x4*>(Xrow + k0 + 8 * g + 4);
#pragma unroll
      for (int i = 0; i < 4; ++i) {
        ah[i] = (short)f2bf(h0[i]); ah[i + 4] = (short)f2bf(h1[i]);
        ax[i] = (short)f2bf(x0[i]); ax[i + 4] = (short)f2bf(x1[i]);
      }
    }
#pragma unroll
    for (int cf = 0; cf < 4; ++cf) {
      bf16x8 bq, bk;
#pragma unroll
      for (int i = 0; i < 8; ++i) {
        int kk = k0 + 8 * g + i;
        bq[i] = (short)f2bf(WQ[(size_t)kk * DK_ + cf * 16 + c]);
        bk[i] = (short)f2bf(WK[(size_t)kk * DK_ + cf * 16 + c]);
      }
      accq[cf] = MFMA16(ah, bq, accq[cf]);
      acck[cf] = MFMA16(ax, bk, acck[cf]);
    }
  }
#pragma unroll
  for (int cf = 0; cf < 4; ++cf) {
    float vq = bQ[cf * 16 + c], vk = bK[cf * 16 + c];
    int ks = cf >> 1;
    int g2 = ((cf & 1) * 16 + c) >> 3;
    int i2 = c & 7;
#pragma unroll
    for (int r = 0; r < 4; ++r) {
      size_t e = ((size_t)(b * 128 + nt * 4 + w) * 2 + ks) * 512 +
                 (g2 * 16 + 4 * g + r) * 8 + i2;
      Qf[e] = f2bf((accq[cf][r] + vq) * 0.125f);
      Kf[e] = f2bf(acck[cf][r] + vk);
    }
  }
}

// ---------------------------------------------------------------------------
// attn: 512 blocks x 256 threads (4 waves). Block = 64 q x 256 d (dh half),
// 2 blocks/CU -> independent barriers de-phase the blocks so one block's
// exp/VALU phase overlaps the other's PV/MFMA phase (R7 showed 1-block
// phase-lock serializes pipes: MFMA+LDS+VALU+L2 summed, not maxed).
// b = bid&7 (XCD pin). S-slab per wave: (qh,kq) in 2x2 -> S[32q][32kv].
// Plds stride 76 u16 (152B): P-writes and pa-reads both <=2-way (was 4-way).
// ---------------------------------------------------------------------------
__global__ __launch_bounds__(256, 2) void attn_kernel(
    const u16* __restrict__ Qf, const u16* __restrict__ Kf,
    const u16* __restrict__ Vf, float* __restrict__ out) {
  int bid = blockIdx.x;
  int b = bid & 7, dh = (bid >> 3) & 1, qt = bid >> 4;
  int q0 = qt * 64;
  int t = threadIdx.x, w = t >> 6, l = t & 63, g = l >> 4, c = l & 15;
  int qh = w >> 1, kq = w & 1;          // S-slab coords (2x2)

  __shared__ u16 Plds[2][64][76];       // P double buffer [q 64][kv 64]
  __shared__ float Lp[2][64];

  // resident Q A-frags: slab = qt*4 + qh*2 + qf
  bf16x8 aq[2][2];
#pragma unroll
  for (int qf = 0; qf < 2; ++qf)
#pragma unroll
    for (int ks = 0; ks < 2; ++ks)
      aq[qf][ks] = *reinterpret_cast<const bf16x8*>(
          Qf + ((size_t)(b * 128 + qt * 4 + qh * 2 + qf) * 2 + ks) * 512 + l * 8);

  f32x4 o[4][4];
#pragma unroll
  for (int a = 0; a < 4; ++a)
#pragma unroll
    for (int d = 0; d < 4; ++d) o[a][d] = (f32x4){0.f, 0.f, 0.f, 0.f};
  float lp[2][4];
#pragma unroll
  for (int a = 0; a < 2; ++a)
#pragma unroll
    for (int r = 0; r < 4; ++r) lp[a][r] = 0.f;

  // frag-line bases (u16 elems)
  // K slab for tile kvt, sub kf: kvt*4 + kq*2 + kf
  const u16* Kbase = Kf + (size_t)(b * 128 + kq * 2) * 2 * 512 + l * 8;
  // V tile dt = dh*16 + w*4 + df
  const u16* Vbase = Vf + ((size_t)(b * 32 + dh * 16 + w * 4) * 32) * 2 * 512 + l * 8;

  bf16x8 vA[8], vB[8], kA[4], kB[4];
#pragma unroll
  for (int kf = 0; kf < 2; ++kf)
#pragma unroll
    for (int ks = 0; ks < 2; ++ks)
      kA[kf * 2 + ks] = *reinterpret_cast<const bf16x8*>(
          Kbase + ((size_t)kf * 2 + ks) * 512);
#pragma unroll
  for (int ks = 0; ks < 2; ++ks)
#pragma unroll
    for (int df = 0; df < 4; ++df)
      vA[ks * 4 + df] = *reinterpret_cast<const bf16x8*>(
          Vbase + ((size_t)df * 32 * 2 + ks) * 512);

  auto body = [&](bf16x8 (&vC)[8], bf16x8 (&kC)[4],
                  bf16x8 (&vN)[8], bf16x8 (&kN)[4], int i) {
    const int pb = i & 1;
    const int kvn = (i + 1) & 31;

    // ---- S = Q/8 @ K^T for this wave's [32q][32kv] slab (register-only)
    f32x4 s[2][2];
#pragma unroll
    for (int qf = 0; qf < 2; ++qf)
#pragma unroll
      for (int kf = 0; kf < 2; ++kf) {
        s[qf][kf] = (f32x4){0.f, 0.f, 0.f, 0.f};
        s[qf][kf] = MFMA16(aq[qf][0], kC[kf * 2 + 0], s[qf][kf]);
        s[qf][kf] = MFMA16(aq[qf][1], kC[kf * 2 + 1], s[qf][kf]);
      }

    // ---- P = exp(S), partial sums, write P slab (bf16)
#pragma unroll
    for (int qf = 0; qf < 2; ++qf)
#pragma unroll
      for (int kf = 0; kf < 2; ++kf)
#pragma unroll
        for (int r = 0; r < 4; ++r) {
          float p = __expf(s[qf][kf][r]);
          lp[qf][r] += p;
          Plds[pb][qh * 32 + qf * 16 + 4 * g + r][kq * 32 + kf * 16 + c] = f2bf(p);
        }

    // ---- single full barrier per iter (outstanding vmem is one iter old)
    __syncthreads();

    // ---- issue next-tile K/V frag loads (contiguous 1KB each)
#pragma unroll
    for (int kf = 0; kf < 2; ++kf)
#pragma unroll
      for (int ks = 0; ks < 2; ++ks)
        kN[kf * 2 + ks] = *reinterpret_cast<const bf16x8*>(
            Kbase + ((size_t)(kvn * 4 + kf) * 2 + ks) * 512);
#pragma unroll
    for (int ks = 0; ks < 2; ++ks)
#pragma unroll
      for (int df = 0; df < 4; ++df)
        vN[ks * 4 + df] = *reinterpret_cast<const bf16x8*>(
            Vbase + (((size_t)df * 32 + kvn) * 2 + ks) * 512);

    // ---- O += P @ V  (P from LDS, V from registers), prioritized
    bf16x8 pa0, pa1, pa2, pa3;
    __builtin_amdgcn_s_setprio(1);
#pragma unroll
    for (int ks = 0; ks < 2; ++ks) {
      pa0 = *reinterpret_cast<const bf16x8*>(&Plds[pb][c][ks * 32 + 8 * g]);
      pa1 = *reinterpret_cast<const bf16x8*>(&Plds[pb][16 + c][ks * 32 + 8 * g]);
      pa2 = *reinterpret_cast<const bf16x8*>(&Plds[pb][32 + c][ks * 32 + 8 * g]);
      pa3 = *reinterpret_cast<const bf16x8*>(&Plds[pb][48 + c][ks * 32 + 8 * g]);
#pragma unroll
      for (int df = 0; df < 4; ++df) {
        o[0][df] = MFMA16(pa0, vC[ks * 4 + df], o[0][df]);
        o[1][df] = MFMA16(pa1, vC[ks * 4 + df], o[1][df]);
        o[2][df] = MFMA16(pa2, vC[ks * 4 + df], o[2][df]);
        o[3][df] = MFMA16(pa3, vC[ks * 4 + df], o[3][df]);
      }
    }
    __builtin_amdgcn_s_setprio(0);
  };

#pragma unroll 1
  for (int i = 0; i < 32; i += 2) {
    body(vA, kA, vB, kB, i);
    body(vB, kB, vA, kA, i + 1);
  }

  // ---- denominator: reduce lp over 16 c-lanes, combine across kq waves
#pragma unroll
  for (int qf = 0; qf < 2; ++qf)
#pragma unroll
    for (int r = 0; r < 4; ++r) {
      float v = lp[qf][r];
      v += __shfl_xor(v, 1); v += __shfl_xor(v, 2);
      v += __shfl_xor(v, 4); v += __shfl_xor(v, 8);
      lp[qf][r] = v;
    }
  if (c == 0) {
#pragma unroll
    for (int qf = 0; qf < 2; ++qf)
#pragma unroll
      for (int r = 0; r < 4; ++r)
        Lp[kq][qh * 32 + qf * 16 + 4 * g + r] = lp[qf][r];
  }
  __syncthreads();

  float* outb = out + ((size_t)b * N_ + q0) * D_ + dh * 256;
#pragma unroll
  for (int qf2 = 0; qf2 < 4; ++qf2)
#pragma unroll
    for (int r = 0; r < 4; ++r) {
      int ql = qf2 * 16 + 4 * g + r;
      float L = Lp[0][ql] + Lp[1][ql];
      float inv = 1.0f / L;
#pragma unroll
      for (int df = 0; df < 4; ++df)
        outb[(size_t)ql * D_ + w * 64 + df * 16 + c] = o[qf2][df][r] * inv;
    }
}

// ---------------------------------------------------------------------------
extern "C" void kernel_launch(void* const* d_in, const int* in_sizes, int n_in,
                              void* d_out, int out_size, void* d_ws, size_t ws_size,
                              hipStream_t stream) {
  const float* X  = (const float*)d_in[0];
  const float* h  = (const float*)d_in[1];
  const float* WQ = (const float*)d_in[2];
  const float* bQ = (const float*)d_in[3];
  const float* WK = (const float*)d_in[4];
  const float* bK = (const float*)d_in[5];
  float* out = (float*)d_out;

  u16* Vf = (u16*)d_ws;                                // 16 MB
  u16* Qf = Vf + (size_t)B_ * D_ * N_;                 // 2 MB
  u16* Kf = Qf + (size_t)B_ * N_ * DK_;                // 2 MB

  vt_kernel<<<dim3(2048), dim3(256), 0, stream>>>(X, Vf);
  proj_kernel<<<dim3(256), dim3(256), 0, stream>>>(h, X, WQ, bQ, WK, bK, Qf, Kf);
  attn_kernel<<<dim3(512), dim3(256), 0, stream>>>(Qf, Kf, Vf, out);
}

// Round 9
// 82.013 us; speedup vs baseline: 1.0324x; 1.0324x over previous
//
#include <hip/hip_runtime.h>
#include <hip/hip_bf16.h>

#define B_ 8
#define N_ 2048
#define D_ 512
#define DK_ 64

typedef float f32x4 __attribute__((ext_vector_type(4)));
typedef short bf16x8 __attribute__((ext_vector_type(8)));
typedef unsigned short u16;

__device__ __forceinline__ u16 f2bf(float f) {
  union { float f; unsigned u; } v; v.f = f;
  unsigned r = v.u + 0x7FFFu + ((v.u >> 16) & 1u);  // RNE, inputs finite
  return (u16)(r >> 16);
}

#define MFMA16(a, b, cacc) __builtin_amdgcn_mfma_f32_16x16x32_bf16((a), (b), (cacc), 0, 0, 0)

// ===========================================================================
// Fragment layouts (every attn global load = 64 lanes x 16B contiguous 1KB):
//  Qf/Kf: elem((b*128 + slab)*2 + ks)*512 + lane*8 + i
//         holds  M[slab*16 + (lane&15)][ks*32 + (lane>>4)*8 + i]
//  Vf:    elem(((b*32 + dt)*32 + kvt)*2 + ks)*512 + lane*8 + i
//         holds  X[kvt*64 + ks*32 + (lane>>4)*8 + i][dt*16 + (lane&15)]
// ===========================================================================

// ---------------------------------------------------------------------------
// Kernel 1 (validated): X f32 -> Vf bf16 frag layout.
// ---------------------------------------------------------------------------
__global__ __launch_bounds__(256) void vt_kernel(const float* __restrict__ X,
                                                 u16* __restrict__ Vf) {
  int bid = blockIdx.x;
  int dt = bid & 7, nt = (bid >> 3) & 31, b = bid >> 8;
  int n0 = nt * 64, d0 = dt * 64;
  __shared__ u16 T[64 * 72];  // T[d_local][n_local]
  int t = threadIdx.x;
  const float* Xb = X + ((size_t)b * N_ + n0) * D_ + d0;
#pragma unroll
  for (int p = 0; p < 4; ++p) {
    int r = p * 16 + (t >> 4);      // n_local
    int c4 = (t & 15) * 4;          // d_local base
    f32x4 v = *reinterpret_cast<const f32x4*>(Xb + (size_t)r * D_ + c4);
#pragma unroll
    for (int j = 0; j < 4; ++j) T[(c4 + j) * 72 + r] = f2bf(v[j]);
  }
  __syncthreads();
  int w = t >> 6, l = t & 63, g = l >> 4, c = l & 15;
#pragma unroll
  for (int ks = 0; ks < 2; ++ks) {
    bf16x8 v = *reinterpret_cast<const bf16x8*>(&T[(w * 16 + c) * 72 + ks * 32 + 8 * g]);
    *reinterpret_cast<bf16x8*>(
        Vf + (((size_t)(b * 32 + dt * 4 + w) * 32 + nt) * 2 + ks) * 512 + l * 8) = v;
  }
}

// ---------------------------------------------------------------------------
// Kernel 2 (validated): Qf = (h@WQ + bQ)/8, Kf = X@WK + bK, frag layout.
// ---------------------------------------------------------------------------
__global__ __launch_bounds__(256) void proj_kernel(
    const float* __restrict__ h, const float* __restrict__ X,
    const float* __restrict__ WQ, const float* __restrict__ bQ,
    const float* __restrict__ WK, const float* __restrict__ bK,
    u16* __restrict__ Qf, u16* __restrict__ Kf) {
  int bid = blockIdx.x;
  int b = bid & 7, nt = bid >> 3;
  int n0 = nt * 64;
  int t = threadIdx.x, w = t >> 6, l = t & 63, g = l >> 4, c = l & 15;
  int arow = n0 + w * 16 + c;
  const float* hrow = h + ((size_t)b * N_ + arow) * D_;
  const float* Xrow = X + ((size_t)b * N_ + arow) * D_;
  f32x4 accq[4], acck[4];
#pragma unroll
  for (int cf = 0; cf < 4; ++cf) {
    accq[cf] = (f32x4){0.f, 0.f, 0.f, 0.f};
    acck[cf] = (f32x4){0.f, 0.f, 0.f, 0.f};
  }
  for (int k0 = 0; k0 < D_; k0 += 32) {
    bf16x8 ah, ax;
    {
      f32x4 h0 = *reinterpret_cast<const f32x4*>(hrow + k0 + 8 * g);
      f32x4 h1 = *reinterpret_cast<const f32x4*>(hrow + k0 + 8 * g + 4);
      f32x4 x0 = *reinterpret_cast<const f32x4*>(Xrow + k0 + 8 * g);
      f32x4 x1 = *reinterpret_cast<const f32x4*>(Xrow + k0 + 8 * g + 4);
#pragma unroll
      for (int i = 0; i < 4; ++i) {
        ah[i] = (short)f2bf(h0[i]); ah[i + 4] = (short)f2bf(h1[i]);
        ax[i] = (short)f2bf(x0[i]); ax[i + 4] = (short)f2bf(x1[i]);
      }
    }
#pragma unroll
    for (int cf = 0; cf < 4; ++cf) {
      bf16x8 bq, bk;
#pragma unroll
      for (int i = 0; i < 8; ++i) {
        int kk = k0 + 8 * g + i;
        bq[i] = (short)f2bf(WQ[(size_t)kk * DK_ + cf * 16 + c]);
        bk[i] = (short)f2bf(WK[(size_t)kk * DK_ + cf * 16 + c]);
      }
      accq[cf] = MFMA16(ah, bq, accq[cf]);
      acck[cf] = MFMA16(ax, bk, acck[cf]);
    }
  }
#pragma unroll
  for (int cf = 0; cf < 4; ++cf) {
    float vq = bQ[cf * 16 + c], vk = bK[cf * 16 + c];
    int ks = cf >> 1;
    int g2 = ((cf & 1) * 16 + c) >> 3;
    int i2 = c & 7;
#pragma unroll
    for (int r = 0; r < 4; ++r) {
      size_t e = ((size_t)(b * 128 + nt * 4 + w) * 2 + ks) * 512 +
                 (g2 * 16 + 4 * g + r) * 8 + i2;
      Qf[e] = f2bf((accq[cf][r] + vq) * 0.125f);
      Kf[e] = f2bf(acck[cf][r] + vk);
    }
  }
}

// ---------------------------------------------------------------------------
// attn: 256 blocks x 512 threads (8 waves), 64q x 512d per block (R7 geom,
// no duplication). T15 software pipeline: each iter computes S/exp/P-write
// for tile i+1, then PV for tile i -- exp(i+1) (VALU) and PV(i) (MFMA+LDS)
// are independent adjacent code so the scheduler interleaves pipes within
// one wave. One barrier per iter (unchanged hazard structure). Plds stride
// 76 u16 (R8-proven: bank conflicts = 0).
// ---------------------------------------------------------------------------
__global__ __launch_bounds__(512, 1) void attn_kernel(
    const u16* __restrict__ Qf, const u16* __restrict__ Kf,
    const u16* __restrict__ Vf, float* __restrict__ out) {
  int bid = blockIdx.x;
  int b = bid & 7, qt = bid >> 3;
  int q0 = qt * 64;
  int t = threadIdx.x, w = t >> 6, l = t & 63, g = l >> 4, c = l & 15;
  int qh = w >> 2, kq = w & 3;          // S-slab coords

  __shared__ u16 Plds[2][64][76];       // P double buffer [q 64][kv 64]
  __shared__ float Lp[4][64];

  // resident Q A-frags: slab = qt*4 + qh*2 + qf
  bf16x8 aq[2][2];
#pragma unroll
  for (int qf = 0; qf < 2; ++qf)
#pragma unroll
    for (int ks = 0; ks < 2; ++ks)
      aq[qf][ks] = *reinterpret_cast<const bf16x8*>(
          Qf + ((size_t)(b * 128 + qt * 4 + qh * 2 + qf) * 2 + ks) * 512 + l * 8);

  f32x4 o[4][4];
#pragma unroll
  for (int a = 0; a < 4; ++a)
#pragma unroll
    for (int d = 0; d < 4; ++d) o[a][d] = (f32x4){0.f, 0.f, 0.f, 0.f};
  float lp[2][4];
#pragma unroll
  for (int a = 0; a < 2; ++a)
#pragma unroll
    for (int r = 0; r < 4; ++r) lp[a][r] = 0.f;

  // frag-line bases (u16 elems); K slab for tile kvt = kvt*4 + kq
  const u16* Kbase = Kf + (size_t)(b * 128 + kq) * 2 * 512 + l * 8;
  const u16* Vbase = Vf + ((size_t)(b * 32 + w * 4) * 32) * 2 * 512 + l * 8;

  bf16x8 vA[8], vB[8], kA[2], kB[2];

  // ---- prologue: k0->kA, v0->vA, k1->kB; S(0); P(0)->buf0; barrier
#pragma unroll
  for (int ks = 0; ks < 2; ++ks)
    kA[ks] = *reinterpret_cast<const bf16x8*>(Kbase + (size_t)ks * 512);
#pragma unroll
  for (int ks = 0; ks < 2; ++ks)
#pragma unroll
    for (int df = 0; df < 4; ++df)
      vA[ks * 4 + df] = *reinterpret_cast<const bf16x8*>(
          Vbase + ((size_t)df * 32 * 2 + ks) * 512);
#pragma unroll
  for (int ks = 0; ks < 2; ++ks)
    kB[ks] = *reinterpret_cast<const bf16x8*>(Kbase + ((size_t)4 * 2 + ks) * 512);
  {
    f32x4 s0 = (f32x4){0.f, 0.f, 0.f, 0.f};
    f32x4 s1 = (f32x4){0.f, 0.f, 0.f, 0.f};
    s0 = MFMA16(aq[0][0], kA[0], s0); s0 = MFMA16(aq[0][1], kA[1], s0);
    s1 = MFMA16(aq[1][0], kA[0], s1); s1 = MFMA16(aq[1][1], kA[1], s1);
#pragma unroll
    for (int r = 0; r < 4; ++r) {
      float p0 = __expf(s0[r]); lp[0][r] += p0;
      Plds[0][qh * 32 + 4 * g + r][kq * 16 + c] = f2bf(p0);
      float p1 = __expf(s1[r]); lp[1][r] += p1;
      Plds[0][qh * 32 + 16 + 4 * g + r][kq * 16 + c] = f2bf(p1);
    }
  }
  __syncthreads();

  // body(i): loads k(i+2)->kL, v(i+1)->vNxt; S(i+1) from kS; write P(i+1);
  //          PV(i) from vCur + Plds[i&1]; barrier.
  auto body = [&](bf16x8 (&vCur)[8], bf16x8 (&vNxt)[8],
                  bf16x8 (&kS)[2], bf16x8 (&kL)[2], int i) {
    const int pbW = (i + 1) & 1, pbR = i & 1;
    const int kv1 = (i + 1) & 31;   // v load target
    const int kv2 = (i + 2) & 31;   // k load target

    // issue prefetch loads (contiguous 1KB frag-lines, stay in flight)
#pragma unroll
    for (int ks = 0; ks < 2; ++ks)
      kL[ks] = *reinterpret_cast<const bf16x8*>(
          Kbase + ((size_t)kv2 * 4 * 2 + ks) * 512);
#pragma unroll
    for (int ks = 0; ks < 2; ++ks)
#pragma unroll
      for (int df = 0; df < 4; ++df)
        vNxt[ks * 4 + df] = *reinterpret_cast<const bf16x8*>(
            Vbase + (((size_t)df * 32 + kv1) * 2 + ks) * 512);

    // ---- S(i+1) = Q/8 @ K^T (register-only; kS loaded one iter ago)
    f32x4 s0 = (f32x4){0.f, 0.f, 0.f, 0.f};
    f32x4 s1 = (f32x4){0.f, 0.f, 0.f, 0.f};
    s0 = MFMA16(aq[0][0], kS[0], s0); s0 = MFMA16(aq[0][1], kS[1], s0);
    s1 = MFMA16(aq[1][0], kS[0], s1); s1 = MFMA16(aq[1][1], kS[1], s1);

    // ---- exp(i+1) + P-write (VALU+LDS)  ... independent of PV(i) below:
    // the scheduler interleaves these with the PV MFMAs.
#pragma unroll
    for (int r = 0; r < 4; ++r) {
      float p0 = __expf(s0[r]); lp[0][r] += p0;
      Plds[pbW][qh * 32 + 4 * g + r][kq * 16 + c] = f2bf(p0);
      float p1 = __expf(s1[r]); lp[1][r] += p1;
      Plds[pbW][qh * 32 + 16 + 4 * g + r][kq * 16 + c] = f2bf(p1);
    }

    // ---- PV(i): O += P(i) @ V(i)  (P from buf[pbR] -- written before the
    // previous barrier; V from registers)
    bf16x8 pa0, pa1, pa2, pa3;
    __builtin_amdgcn_s_setprio(1);
#pragma unroll
    for (int ks = 0; ks < 2; ++ks) {
      pa0 = *reinterpret_cast<const bf16x8*>(&Plds[pbR][c][ks * 32 + 8 * g]);
      pa1 = *reinterpret_cast<const bf16x8*>(&Plds[pbR][16 + c][ks * 32 + 8 * g]);
      pa2 = *reinterpret_cast<const bf16x8*>(&Plds[pbR][32 + c][ks * 32 + 8 * g]);
      pa3 = *reinterpret_cast<const bf16x8*>(&Plds[pbR][48 + c][ks * 32 + 8 * g]);
#pragma unroll
      for (int df = 0; df < 4; ++df) {
        o[0][df] = MFMA16(pa0, vCur[ks * 4 + df], o[0][df]);
        o[1][df] = MFMA16(pa1, vCur[ks * 4 + df], o[1][df]);
        o[2][df] = MFMA16(pa2, vCur[ks * 4 + df], o[2][df]);
        o[3][df] = MFMA16(pa3, vCur[ks * 4 + df], o[3][df]);
      }
    }
    __builtin_amdgcn_s_setprio(0);

    // ---- one barrier per iter: orders P(i+1) writes before iter-(i+1)
    // reads, and buf[pbR] reads before iter-(i+1) overwrites it.
    __syncthreads();
  };

#pragma unroll 1
  for (int i = 0; i < 30; i += 2) {
    body(vA, vB, kB, kA, i);
    body(vB, vA, kA, kB, i + 1);
  }
  body(vA, vB, kB, kA, 30);   // S(31)+PV(30); loads wrap harmlessly

  // ---- epilogue: PV(31) (P in buf1, v31 in vB)
  {
    bf16x8 pa0, pa1, pa2, pa3;
#pragma unroll
    for (int ks = 0; ks < 2; ++ks) {
      pa0 = *reinterpret_cast<const bf16x8*>(&Plds[1][c][ks * 32 + 8 * g]);
      pa1 = *reinterpret_cast<const bf16x8*>(&Plds[1][16 + c][ks * 32 + 8 * g]);
      pa2 = *reinterpret_cast<const bf16x8*>(&Plds[1][32 + c][ks * 32 + 8 * g]);
      pa3 = *reinterpret_cast<const bf16x8*>(&Plds[1][48 + c][ks * 32 + 8 * g]);
#pragma unroll
      for (int df = 0; df < 4; ++df) {
        o[0][df] = MFMA16(pa0, vB[ks * 4 + df], o[0][df]);
        o[1][df] = MFMA16(pa1, vB[ks * 4 + df], o[1][df]);
        o[2][df] = MFMA16(pa2, vB[ks * 4 + df], o[2][df]);
        o[3][df] = MFMA16(pa3, vB[ks * 4 + df], o[3][df]);
      }
    }
  }

  // ---- denominator: reduce lp over 16 c-lanes, combine across kq waves
#pragma unroll
  for (int qf = 0; qf < 2; ++qf)
#pragma unroll
    for (int r = 0; r < 4; ++r) {
      float v = lp[qf][r];
      v += __shfl_xor(v, 1); v += __shfl_xor(v, 2);
      v += __shfl_xor(v, 4); v += __shfl_xor(v, 8);
      lp[qf][r] = v;
    }
  __syncthreads();
  if (c == 0) {
#pragma unroll
    for (int qf = 0; qf < 2; ++qf)
#pragma unroll
      for (int r = 0; r < 4; ++r)
        Lp[kq][qh * 32 + qf * 16 + 4 * g + r] = lp[qf][r];
  }
  __syncthreads();

  float* outb = out + ((size_t)b * N_ + q0) * D_;
#pragma unroll
  for (int qf2 = 0; qf2 < 4; ++qf2)
#pragma unroll
    for (int r = 0; r < 4; ++r) {
      int ql = qf2 * 16 + 4 * g + r;
      float L = Lp[0][ql] + Lp[1][ql] + Lp[2][ql] + Lp[3][ql];
      float inv = 1.0f / L;
#pragma unroll
      for (int df = 0; df < 4; ++df)
        outb[(size_t)ql * D_ + w * 64 + df * 16 + c] = o[qf2][df][r] * inv;
    }
}

// ---------------------------------------------------------------------------
extern "C" void kernel_launch(void* const* d_in, const int* in_sizes, int n_in,
                              void* d_out, int out_size, void* d_ws, size_t ws_size,
                              hipStream_t stream) {
  const float* X  = (const float*)d_in[0];
  const float* h  = (const float*)d_in[1];
  const float* WQ = (const float*)d_in[2];
  const float* bQ = (const float*)d_in[3];
  const float* WK = (const float*)d_in[4];
  const float* bK = (const float*)d_in[5];
  float* out = (float*)d_out;

  u16* Vf = (u16*)d_ws;                                // 16 MB
  u16* Qf = Vf + (size_t)B_ * D_ * N_;                 // 2 MB
  u16* Kf = Qf + (size_t)B_ * N_ * DK_;                // 2 MB

  vt_kernel<<<dim3(2048), dim3(256), 0, stream>>>(X, Vf);
  proj_kernel<<<dim3(256), dim3(256), 0, stream>>>(h, X, WQ, bQ, WK, bK, Qf, Kf);
  attn_kernel<<<dim3(256), dim3(512), 0, stream>>>(Qf, Kf, Vf, out);
}

// Round 10
// 80.510 us; speedup vs baseline: 1.0517x; 1.0187x over previous
//
#include <hip/hip_runtime.h>
#include <hip/hip_bf16.h>

#define B_ 8
#define N_ 2048
#define D_ 512
#define DK_ 64

typedef float f32x4 __attribute__((ext_vector_type(4)));
typedef short bf16x8 __attribute__((ext_vector_type(8)));
typedef unsigned short u16;

__device__ __forceinline__ u16 f2bf(float f) {
  union { float f; unsigned u; } v; v.f = f;
  unsigned r = v.u + 0x7FFFu + ((v.u >> 16) & 1u);  // RNE, inputs finite
  return (u16)(r >> 16);
}

#define MFMA16(a, b, cacc) __builtin_amdgcn_mfma_f32_16x16x32_bf16((a), (b), (cacc), 0, 0, 0)

// lgkm-only barrier: orders LDS ops across the barrier WITHOUT draining vmcnt,
// so deep global prefetch stays in flight. Safe: all in-flight vmem targets
// per-wave registers (no cross-wave hazard); P-exchange needs lgkm only.
// (Construct validated in R4's passing run.)
#define BARRIER_LGKM() do {                                   \
    asm volatile("s_waitcnt lgkmcnt(0)" ::: "memory");        \
    __builtin_amdgcn_s_barrier();                             \
    asm volatile("" ::: "memory");                            \
  } while (0)

// ===========================================================================
// Fragment layouts (every attn global load = 64 lanes x 16B contiguous 1KB):
//  Qf/Kf: elem((b*128 + slab)*2 + ks)*512 + lane*8 + i
//         holds  M[slab*16 + (lane&15)][ks*32 + (lane>>4)*8 + i]
//  Vf:    elem(((b*32 + dt)*32 + nt)*2 + ks)*512 + lane*8 + i
//         holds  X[nt*64 + ks*32 + (lane>>4)*8 + i][dt*16 + (lane&15)]
// ===========================================================================

// ---------------------------------------------------------------------------
// Kernel 1 (validated): X f32 -> Vf bf16 frag layout.
// ---------------------------------------------------------------------------
__global__ __launch_bounds__(256) void vt_kernel(const float* __restrict__ X,
                                                 u16* __restrict__ Vf) {
  int bid = blockIdx.x;
  int dt = bid & 7, nt = (bid >> 3) & 31, b = bid >> 8;
  int n0 = nt * 64, d0 = dt * 64;
  __shared__ u16 T[64 * 72];  // T[d_local][n_local]
  int t = threadIdx.x;
  const float* Xb = X + ((size_t)b * N_ + n0) * D_ + d0;
#pragma unroll
  for (int p = 0; p < 4; ++p) {
    int r = p * 16 + (t >> 4);      // n_local
    int c4 = (t & 15) * 4;          // d_local base
    f32x4 v = *reinterpret_cast<const f32x4*>(Xb + (size_t)r * D_ + c4);
#pragma unroll
    for (int j = 0; j < 4; ++j) T[(c4 + j) * 72 + r] = f2bf(v[j]);
  }
  __syncthreads();
  int w = t >> 6, l = t & 63, g = l >> 4, c = l & 15;
#pragma unroll
  for (int ks = 0; ks < 2; ++ks) {
    bf16x8 v = *reinterpret_cast<const bf16x8*>(&T[(w * 16 + c) * 72 + ks * 32 + 8 * g]);
    *reinterpret_cast<bf16x8*>(
        Vf + (((size_t)(b * 32 + dt * 4 + w) * 32 + nt) * 2 + ks) * 512 + l * 8) = v;
  }
}

// ---------------------------------------------------------------------------
// Kernel 2 (validated): Qf = (h@WQ + bQ)/8, Kf = X@WK + bK, frag layout.
// ---------------------------------------------------------------------------
__global__ __launch_bounds__(256) void proj_kernel(
    const float* __restrict__ h, const float* __restrict__ X,
    const float* __restrict__ WQ, const float* __restrict__ bQ,
    const float* __restrict__ WK, const float* __restrict__ bK,
    u16* __restrict__ Qf, u16* __restrict__ Kf) {
  int bid = blockIdx.x;
  int b = bid & 7, nt = bid >> 3;
  int n0 = nt * 64;
  int t = threadIdx.x, w = t >> 6, l = t & 63, g = l >> 4, c = l & 15;
  int arow = n0 + w * 16 + c;
  const float* hrow = h + ((size_t)b * N_ + arow) * D_;
  const float* Xrow = X + ((size_t)b * N_ + arow) * D_;
  f32x4 accq[4], acck[4];
#pragma unroll
  for (int cf = 0; cf < 4; ++cf) {
    accq[cf] = (f32x4){0.f, 0.f, 0.f, 0.f};
    acck[cf] = (f32x4){0.f, 0.f, 0.f, 0.f};
  }
  for (int k0 = 0; k0 < D_; k0 += 32) {
    bf16x8 ah, ax;
    {
      f32x4 h0 = *reinterpret_cast<const f32x4*>(hrow + k0 + 8 * g);
      f32x4 h1 = *reinterpret_cast<const f32x4*>(hrow + k0 + 8 * g + 4);
      f32x4 x0 = *reinterpret_cast<const f32x4*>(Xrow + k0 + 8 * g);
      f32x4 x1 = *reinterpret_cast<const f32x4*>(Xrow + k0 + 8 * g + 4);
#pragma unroll
      for (int i = 0; i < 4; ++i) {
        ah[i] = (short)f2bf(h0[i]); ah[i + 4] = (short)f2bf(h1[i]);
        ax[i] = (short)f2bf(x0[i]); ax[i + 4] = (short)f2bf(x1[i]);
      }
    }
#pragma unroll
    for (int cf = 0; cf < 4; ++cf) {
      bf16x8 bq, bk;
#pragma unroll
      for (int i = 0; i < 8; ++i) {
        int kk = k0 + 8 * g + i;
        bq[i] = (short)f2bf(WQ[(size_t)kk * DK_ + cf * 16 + c]);
        bk[i] = (short)f2bf(WK[(size_t)kk * DK_ + cf * 16 + c]);
      }
      accq[cf] = MFMA16(ah, bq, accq[cf]);
      acck[cf] = MFMA16(ax, bk, acck[cf]);
    }
  }
#pragma unroll
  for (int cf = 0; cf < 4; ++cf) {
    float vq = bQ[cf * 16 + c], vk = bK[cf * 16 + c];
    int ks = cf >> 1;
    int g2 = ((cf & 1) * 16 + c) >> 3;
    int i2 = c & 7;
#pragma unroll
    for (int r = 0; r < 4; ++r) {
      size_t e = ((size_t)(b * 128 + nt * 4 + w) * 2 + ks) * 512 +
                 (g2 * 16 + 4 * g + r) * 8 + i2;
      Qf[e] = f2bf((accq[cf][r] + vq) * 0.125f);
      Kf[e] = f2bf(acck[cf][r] + vk);
    }
  }
}

// ---------------------------------------------------------------------------
// attn: 256 blocks x 512 threads (8 waves), 64q x 512d per block.
// KVBLK=32 (64 windows). K/V register-buffered 4-DEEP (loads consumed ~3
// windows after issue -> congested L2 latency fully covered), and the
// per-window barrier is LGKM-ONLY so the deep prefetch is never drained
// (R6-R9 plateau diagnosis: __syncthreads vmcnt(0) drain made every window
// wait one full load latency -> schedule-insensitive ~4000cy equilibrium).
// Wave w: S-duty slab qh=w>>1 (16q) x kv-half kq=w&1 (16kv); PV d-slice
// w*64..+64. P exchange via Plds dbuf (stride 40 u16: 16B-aligned b128,
// <=2-way banks). All reg buffers statically indexed via ref params.
// ---------------------------------------------------------------------------
__global__ __launch_bounds__(512, 1) void attn_kernel(
    const u16* __restrict__ Qf, const u16* __restrict__ Kf,
    const u16* __restrict__ Vf, float* __restrict__ out) {
  int bid = blockIdx.x;
  int b = bid & 7, qt = bid >> 3;
  int q0 = qt * 64;
  int t = threadIdx.x, w = t >> 6, l = t & 63, g = l >> 4, c = l & 15;
  int qh = w >> 1, kq = w & 1;

  __shared__ u16 Plds[2][64][40];   // P dbuf [q 64][kv 32], stride 40 u16
  __shared__ float Lp[2][64];

  // resident Q A-frags for slab qt*4+qh
  bf16x8 aq[2];
#pragma unroll
  for (int ks = 0; ks < 2; ++ks)
    aq[ks] = *reinterpret_cast<const bf16x8*>(
        Qf + ((size_t)(b * 128 + qt * 4 + qh) * 2 + ks) * 512 + l * 8);

  f32x4 o[4][4];
#pragma unroll
  for (int a = 0; a < 4; ++a)
#pragma unroll
    for (int d = 0; d < 4; ++d) o[a][d] = (f32x4){0.f, 0.f, 0.f, 0.f};
  float lp[4] = {0.f, 0.f, 0.f, 0.f};

  // frag-line bases (u16 elems)
  // K frag (tile kvt, ks): elem (b*256 + 4*kvt + 2*kq + ks)*512 + l*8
  const u16* Kbase = Kf + ((size_t)(b * 256 + 2 * kq)) * 512 + l * 8;
  // V frag (f, tile kvt): elem ((b*32 + w*4 + f)*64 + kvt)*512 + l*8
  const u16* Vbase = Vf + ((size_t)(b * 32 + w * 4) * 64) * 512 + l * 8;

  bf16x8 kbuf[4][2], vbuf[4][4];

  // ---- prologue: stage tiles 0..2 (3-deep), S(0), P(0)->buf0, barrier
#pragma unroll
  for (int j = 0; j < 3; ++j) {
#pragma unroll
    for (int ks = 0; ks < 2; ++ks)
      kbuf[j][ks] = *reinterpret_cast<const bf16x8*>(
          Kbase + (size_t)(4 * j + ks) * 512);
#pragma unroll
    for (int f = 0; f < 4; ++f)
      vbuf[j][f] = *reinterpret_cast<const bf16x8*>(
          Vbase + (size_t)(f * 64 + j) * 512);
  }
  {
    f32x4 s = (f32x4){0.f, 0.f, 0.f, 0.f};
    s = MFMA16(aq[0], kbuf[0][0], s);
    s = MFMA16(aq[1], kbuf[0][1], s);
#pragma unroll
    for (int r = 0; r < 4; ++r) {
      float p = __expf(s[r]); lp[r] += p;
      Plds[0][qh * 16 + 4 * g + r][kq * 16 + c] = f2bf(p);
    }
  }
  BARRIER_LGKM();

  // window i: load tile (i+3) -> kL/vL; S(i+1) from kS; P(i+1)->buf[(i+1)&1];
  // PV(i) from Plds[i&1] + vR; lgkm-only barrier.
  auto body = [&](bf16x8 (&kS)[2], bf16x8 (&kL)[2],
                  bf16x8 (&vR)[4], bf16x8 (&vL)[4], int i) {
    const int kvL = (i + 3) & 63;
    const int pbW = (i + 1) & 1, pbR = i & 1;

    // issue prefetch: K first (consumed 2 windows out), then V (3 windows)
#pragma unroll
    for (int ks = 0; ks < 2; ++ks)
      kL[ks] = *reinterpret_cast<const bf16x8*>(
          Kbase + (size_t)(4 * kvL + ks) * 512);
#pragma unroll
    for (int f = 0; f < 4; ++f)
      vL[f] = *reinterpret_cast<const bf16x8*>(
          Vbase + (size_t)(f * 64 + kvL) * 512);

    // ---- S(i+1): one 16q x 16kv C-tile per wave (register-only)
    f32x4 s = (f32x4){0.f, 0.f, 0.f, 0.f};
    s = MFMA16(aq[0], kS[0], s);
    s = MFMA16(aq[1], kS[1], s);

    // ---- exp(i+1) + P-write to buf[pbW]
#pragma unroll
    for (int r = 0; r < 4; ++r) {
      float p = __expf(s[r]); lp[r] += p;
      Plds[pbW][qh * 16 + 4 * g + r][kq * 16 + c] = f2bf(p);
    }

    // ---- PV(i): P A-frags from buf[pbR], V from registers
    bf16x8 pa0 = *reinterpret_cast<const bf16x8*>(&Plds[pbR][c][8 * g]);
    bf16x8 pa1 = *reinterpret_cast<const bf16x8*>(&Plds[pbR][16 + c][8 * g]);
    bf16x8 pa2 = *reinterpret_cast<const bf16x8*>(&Plds[pbR][32 + c][8 * g]);
    bf16x8 pa3 = *reinterpret_cast<const bf16x8*>(&Plds[pbR][48 + c][8 * g]);
    __builtin_amdgcn_s_setprio(1);
#pragma unroll
    for (int dt = 0; dt < 4; ++dt) {
      o[0][dt] = MFMA16(pa0, vR[dt], o[0][dt]);
      o[1][dt] = MFMA16(pa1, vR[dt], o[1][dt]);
      o[2][dt] = MFMA16(pa2, vR[dt], o[2][dt]);
      o[3][dt] = MFMA16(pa3, vR[dt], o[3][dt]);
    }
    __builtin_amdgcn_s_setprio(0);

    // ---- lgkm-only barrier: P writes/reads ordered; vmem stays in flight
    BARRIER_LGKM();
  };

#pragma unroll 1
  for (int i = 0; i < 60; i += 4) {
    body(kbuf[1], kbuf[3], vbuf[0], vbuf[3], i);
    body(kbuf[2], kbuf[0], vbuf[1], vbuf[0], i + 1);
    body(kbuf[3], kbuf[1], vbuf[2], vbuf[1], i + 2);
    body(kbuf[0], kbuf[2], vbuf[3], vbuf[2], i + 3);
  }
  body(kbuf[1], kbuf[3], vbuf[0], vbuf[3], 60);
  body(kbuf[2], kbuf[0], vbuf[1], vbuf[0], 61);
  body(kbuf[3], kbuf[1], vbuf[2], vbuf[1], 62);

  // ---- epilogue: PV(63) (P in buf1, V in vbuf[3])
  {
    bf16x8 pa0 = *reinterpret_cast<const bf16x8*>(&Plds[1][c][8 * g]);
    bf16x8 pa1 = *reinterpret_cast<const bf16x8*>(&Plds[1][16 + c][8 * g]);
    bf16x8 pa2 = *reinterpret_cast<const bf16x8*>(&Plds[1][32 + c][8 * g]);
    bf16x8 pa3 = *reinterpret_cast<const bf16x8*>(&Plds[1][48 + c][8 * g]);
#pragma unroll
    for (int dt = 0; dt < 4; ++dt) {
      o[0][dt] = MFMA16(pa0, vbuf[3][dt], o[0][dt]);
      o[1][dt] = MFMA16(pa1, vbuf[3][dt], o[1][dt]);
      o[2][dt] = MFMA16(pa2, vbuf[3][dt], o[2][dt]);
      o[3][dt] = MFMA16(pa3, vbuf[3][dt], o[3][dt]);
    }
  }

  // ---- denominator: reduce lp over 16 c-lanes, combine the 2 kq halves
#pragma unroll
  for (int r = 0; r < 4; ++r) {
    float v = lp[r];
    v += __shfl_xor(v, 1); v += __shfl_xor(v, 2);
    v += __shfl_xor(v, 4); v += __shfl_xor(v, 8);
    lp[r] = v;
  }
  if (c == 0) {
#pragma unroll
    for (int r = 0; r < 4; ++r) Lp[kq][qh * 16 + 4 * g + r] = lp[r];
  }
  __syncthreads();

  float* outb = out + ((size_t)b * N_ + q0) * D_;
#pragma unroll
  for (int qf2 = 0; qf2 < 4; ++qf2)
#pragma unroll
    for (int r = 0; r < 4; ++r) {
      int ql = qf2 * 16 + 4 * g + r;
      float L = Lp[0][ql] + Lp[1][ql];
      float inv = 1.0f / L;
#pragma unroll
      for (int df = 0; df < 4; ++df)
        outb[(size_t)ql * D_ + w * 64 + df * 16 + c] = o[qf2][df][r] * inv;
    }
}

// ---------------------------------------------------------------------------
extern "C" void kernel_launch(void* const* d_in, const int* in_sizes, int n_in,
                              void* d_out, int out_size, void* d_ws, size_t ws_size,
                              hipStream_t stream) {
  const float* X  = (const float*)d_in[0];
  const float* h  = (const float*)d_in[1];
  const float* WQ = (const float*)d_in[2];
  const float* bQ = (const float*)d_in[3];
  const float* WK = (const float*)d_in[4];
  const float* bK = (const float*)d_in[5];
  float* out = (float*)d_out;

  u16* Vf = (u16*)d_ws;                                // 16 MB
  u16* Qf = Vf + (size_t)B_ * D_ * N_;                 // 2 MB
  u16* Kf = Qf + (size_t)B_ * N_ * DK_;                // 2 MB

  vt_kernel<<<dim3(2048), dim3(256), 0, stream>>>(X, Vf);
  proj_kernel<<<dim3(256), dim3(256), 0, stream>>>(h, X, WQ, bQ, WK, bK, Qf, Kf);
  attn_kernel<<<dim3(256), dim3(512), 0, stream>>>(Qf, Kf, Vf, out);
}